// Round 16
// baseline (207.139 us; speedup 1.0000x reference)
//
#include <hip/hip_runtime.h>
#include <hip/hip_bf16.h>

// B=512, S=16384, C=3. logits f32 [B,S,3], labels i32 [B,S].
// out = mean over valid of ( -w[lab]*logp[lab] - 2.0*(true_sw & pred_near)
//                            + 1.5*(pred_sw & ~true_near & has_true_row & valid) )
// TOL=5 window, per-row edge-clipped.
//
// R15 post-mortem: all k1 variants ~58-60us (~2.2 TB/s) with nothing saturated
// -> latency-bound, MLP never realized (arrays let scheduler re-serialize;
// r14 VGPR=24 proved it). This round: 16 pos/thread, loads as NAMED ext_vector
// registers (no arrays), nontemporal, then sched_barrier(0) to pin all 16
// loads before any compute. One-shot grid (no loop). No atomics, no LDS in
// stream path.

#define TOL 5
#define BLOCK 256

typedef unsigned long long u64;
typedef unsigned int u32;
typedef unsigned short u16;
typedef float  f32x4 __attribute__((ext_vector_type(4)));
typedef int    i32x4 __attribute__((ext_vector_type(4)));
typedef unsigned short u16x4 __attribute__((ext_vector_type(4)));

// process one position; accumulate CE and set mask bits
__device__ __forceinline__ void pos1(float l0, float l1, float l2, int lab, int j,
                                     float& bsum, int& vcnt, u32& pb, u32& tb, u32& vb)
{
    const bool valid = (lab != -100);
    const int ls = valid ? lab : 0;
    const float mx = fmaxf(l0, fmaxf(l1, l2));
    const float se = __expf(l0 - mx) + __expf(l1 - mx) + __expf(l2 - mx);
    const float lse = mx + __logf(se);
    const float lpick = (ls == 0 ? l0 : (ls == 1 ? l1 : l2)) - lse;
    const float w = (ls == 0) ? 0.1f : 5.0f;
    bsum += valid ? (-w * lpick) : 0.f;
    vcnt += valid ? 1 : 0;
    pb |= (u32)(fmaxf(l1, l2) > l0) << j;   // argmax>=1 iff max(l1,l2)>l0
    tb |= (u32)(lab >= 1) << j;             // -100 excluded
    vb |= (u32)valid << j;
}

// ---------------- K1: one-shot, 16 positions/thread ----------------
__global__ __launch_bounds__(BLOCK) void k1_mlp(
    const float* __restrict__ logits, const int* __restrict__ labels,
    u32* __restrict__ pt32, u16* __restrict__ v16,
    double* __restrict__ pbsum, int* __restrict__ pvcnt)
{
    const int tid = threadIdx.x;
    const long long gid = (long long)blockIdx.x * BLOCK + tid;
    const long long p0 = gid * 16;

    const f32x4* lf = (const f32x4*)(logits + 3 * p0);   // 48 floats, 192B-aligned
    const i32x4* li = (const i32x4*)(labels + p0);       // 16 ints, 64B-aligned

    // ---- 16 independent nontemporal loads into NAMED registers ----
    f32x4 f0 = __builtin_nontemporal_load(lf + 0);
    f32x4 f1 = __builtin_nontemporal_load(lf + 1);
    f32x4 f2 = __builtin_nontemporal_load(lf + 2);
    f32x4 f3 = __builtin_nontemporal_load(lf + 3);
    f32x4 f4 = __builtin_nontemporal_load(lf + 4);
    f32x4 f5 = __builtin_nontemporal_load(lf + 5);
    f32x4 f6 = __builtin_nontemporal_load(lf + 6);
    f32x4 f7 = __builtin_nontemporal_load(lf + 7);
    f32x4 f8 = __builtin_nontemporal_load(lf + 8);
    f32x4 f9 = __builtin_nontemporal_load(lf + 9);
    f32x4 fa = __builtin_nontemporal_load(lf + 10);
    f32x4 fb = __builtin_nontemporal_load(lf + 11);
    i32x4 b0 = __builtin_nontemporal_load(li + 0);
    i32x4 b1 = __builtin_nontemporal_load(li + 1);
    i32x4 b2 = __builtin_nontemporal_load(li + 2);
    i32x4 b3 = __builtin_nontemporal_load(li + 3);
    __builtin_amdgcn_sched_barrier(0);   // all loads issued before any compute

    float bsum = 0.f;
    int   vcnt = 0;
    u32 pb = 0, tb = 0, vb = 0;

    // positions j: logits float index 3j..3j+2 within f0..fb (compile-time swizzles)
    pos1(f0.x, f0.y, f0.z, b0.x,  0, bsum, vcnt, pb, tb, vb);
    pos1(f0.w, f1.x, f1.y, b0.y,  1, bsum, vcnt, pb, tb, vb);
    pos1(f1.z, f1.w, f2.x, b0.z,  2, bsum, vcnt, pb, tb, vb);
    pos1(f2.y, f2.z, f2.w, b0.w,  3, bsum, vcnt, pb, tb, vb);
    pos1(f3.x, f3.y, f3.z, b1.x,  4, bsum, vcnt, pb, tb, vb);
    pos1(f3.w, f4.x, f4.y, b1.y,  5, bsum, vcnt, pb, tb, vb);
    pos1(f4.z, f4.w, f5.x, b1.z,  6, bsum, vcnt, pb, tb, vb);
    pos1(f5.y, f5.z, f5.w, b1.w,  7, bsum, vcnt, pb, tb, vb);
    pos1(f6.x, f6.y, f6.z, b2.x,  8, bsum, vcnt, pb, tb, vb);
    pos1(f6.w, f7.x, f7.y, b2.y,  9, bsum, vcnt, pb, tb, vb);
    pos1(f7.z, f7.w, f8.x, b2.z, 10, bsum, vcnt, pb, tb, vb);
    pos1(f8.y, f8.z, f8.w, b2.w, 11, bsum, vcnt, pb, tb, vb);
    pos1(f9.x, f9.y, f9.z, b3.x, 12, bsum, vcnt, pb, tb, vb);
    pos1(f9.w, fa.x, fa.y, b3.y, 13, bsum, vcnt, pb, tb, vb);
    pos1(fa.z, fa.w, fb.x, b3.z, 14, bsum, vcnt, pb, tb, vb);
    pos1(fb.y, fb.z, fb.w, b3.w, 15, bsum, vcnt, pb, tb, vb);

    pt32[gid] = pb | (tb << 16);
    v16[gid]  = (u16)vb;

    // block reduce -> per-block partial (no atomics)
#pragma unroll
    for (int off = 32; off; off >>= 1) {
        bsum += __shfl_down(bsum, off);
        vcnt += __shfl_down(vcnt, off);
    }
    __shared__ float wb[BLOCK / 64];
    __shared__ int   wv[BLOCK / 64];
    const int wave = tid >> 6;
    if ((tid & 63) == 0) { wb[wave] = bsum; wv[wave] = vcnt; }
    __syncthreads();
    if (tid == 0) {
        double s = 0.0; int cc = 0;
#pragma unroll
        for (int i = 0; i < BLOCK / 64; ++i) { s += (double)wb[i]; cc += wv[i]; }
        pbsum[blockIdx.x] = s;
        pvcnt[blockIdx.x] = cc;
    }
}

// ---------------- K2: per-row window + counts ----------------
// One block per row; thread t owns 64-pos group t = entries 4t..4t+3 of the row.
__global__ __launch_bounds__(BLOCK) void k2_window(
    const u32* __restrict__ pt32, const u16* __restrict__ v16,
    float* __restrict__ adj_row)
{
    const int row = blockIdx.x;
    const int t = threadIdx.x;

    const i32x4 q = *(const i32x4*)(pt32 + (long long)row * 1024 + 4 * t);   // 16B-aligned
    const u16x4 vq = *(const u16x4*)(v16 + (long long)row * 1024 + 4 * t);   // 8B-aligned

    u64 pm = 0, tm = 0, vm = 0;
#pragma unroll
    for (int i = 0; i < 4; ++i) {
        const u32 w = (u32)((i == 0) ? q.x : (i == 1) ? q.y : (i == 2) ? q.z : q.w);
        const u32 v = (u32)((i == 0) ? vq.x : (i == 1) ? vq.y : (i == 2) ? vq.z : vq.w);
        pm |= (u64)(w & 0xFFFFu) << (16 * i);
        tm |= (u64)(w >> 16) << (16 * i);
        vm |= (u64)v << (16 * i);
    }

    __shared__ u64 pmS[BLOCK], tmS[BLOCK];
    pmS[t] = pm; tmS[t] = tm;
    __syncthreads();

    const u64 pp = (t > 0)         ? pmS[t - 1] : 0ULL;
    const u64 pn = (t < BLOCK - 1) ? pmS[t + 1] : 0ULL;
    const u64 tp = (t > 0)         ? tmS[t - 1] : 0ULL;
    const u64 tn = (t < BLOCK - 1) ? tmS[t + 1] : 0ULL;

    u64 pnear = pm, tnear = tm;
#pragma unroll
    for (int k = 1; k <= TOL; ++k) {
        pnear |= (pm << k) | (pm >> k) | (pp >> (64 - k)) | (pn << (64 - k));
        tnear |= (tm << k) | (tm >> k) | (tp >> (64 - k)) | (tn << (64 - k));
    }

    int reward  = __popcll(tm & pnear);        // true_sw implies valid
    int penalty = __popcll(pm & ~tnear & vm);  // gated by valid
    int ht = (tm != 0ULL) ? 1 : 0;

#pragma unroll
    for (int off = 32; off; off >>= 1) {
        reward  += __shfl_down(reward, off);
        penalty += __shfl_down(penalty, off);
        ht      |= __shfl_down(ht, off);
    }
    __shared__ int rs[BLOCK / 64], ps[BLOCK / 64], hs[BLOCK / 64];
    const int wave = t >> 6;
    if ((t & 63) == 0) { rs[wave] = reward; ps[wave] = penalty; hs[wave] = ht; }
    __syncthreads();
    if (t == 0) {
        int R = 0, P = 0, H = 0;
#pragma unroll
        for (int i = 0; i < BLOCK / 64; ++i) { R += rs[i]; P += ps[i]; H |= hs[i]; }
        adj_row[row] = -2.0f * (float)R + (H ? 1.5f * (float)P : 0.0f);  // exact ints
    }
}

// ---------------- K3: final reduce (one block) ----------------
__global__ __launch_bounds__(BLOCK) void k3_reduce(
    const double* __restrict__ pbsum, const int* __restrict__ pvcnt, int nblocks,
    const float* __restrict__ adj_row, int nrows,
    float* __restrict__ out)
{
    const int t = threadIdx.x;
    double s = 0.0, a = 0.0;
    long long c = 0;
    for (int i = t; i < nblocks; i += BLOCK) { s += pbsum[i]; c += (long long)pvcnt[i]; }
    for (int i = t; i < nrows; i += BLOCK) a += (double)adj_row[i];

#pragma unroll
    for (int off = 32; off; off >>= 1) {
        s += __shfl_down(s, off);
        a += __shfl_down(a, off);
        c += __shfl_down(c, off);
    }
    __shared__ double ss[BLOCK / 64], as[BLOCK / 64];
    __shared__ long long cs[BLOCK / 64];
    const int wave = t >> 6;
    if ((t & 63) == 0) { ss[wave] = s; as[wave] = a; cs[wave] = c; }
    __syncthreads();
    if (t == 0) {
        double S = 0.0, A = 0.0; long long C = 0;
#pragma unroll
        for (int i = 0; i < BLOCK / 64; ++i) { S += ss[i]; A += as[i]; C += cs[i]; }
        out[0] = (float)((S + A) / (double)C);
    }
}

extern "C" void kernel_launch(void* const* d_in, const int* in_sizes, int n_in,
                              void* d_out, int out_size, void* d_ws, size_t ws_size,
                              hipStream_t stream) {
    const float* logits = (const float*)d_in[0];
    const int*   labels = (const int*)d_in[1];
    float* out = (float*)d_out;

    const long long BS = in_sizes[1];          // B*S = 8388608
    const int B = 512;                         // rows (S=16384 -> 256 groups/row)
    const int nthreads_blocks = (int)(BS / (16 * BLOCK));   // 2048 one-shot blocks

    char* ws = (char*)d_ws;
    u32* pt32 = (u32*)ws;                                  // BS/16 u32 = 2 MB
    u16* v16  = (u16*)(pt32 + BS / 16);                    // 1 MB
    double* pbsum = (double*)(v16 + BS / 16);              // 16 KB
    int* pvcnt    = (int*)(pbsum + nthreads_blocks);       // 8 KB
    float* adjrow = (float*)(pvcnt + nthreads_blocks);     // 2 KB

    k1_mlp<<<nthreads_blocks, BLOCK, 0, stream>>>(
        logits, labels, pt32, v16, pbsum, pvcnt);
    k2_window<<<B, BLOCK, 0, stream>>>(pt32, v16, adjrow);
    k3_reduce<<<1, BLOCK, 0, stream>>>(pbsum, pvcnt, nthreads_blocks, adjrow, B, out);
}

// Round 17
// 201.689 us; speedup vs baseline: 1.0270x; 1.0270x over previous
//
#include <hip/hip_runtime.h>
#include <hip/hip_bf16.h>

// B=512, S=16384, C=3. logits f32 [B,S,3], labels i32 [B,S].
// out = mean over valid of ( -w[lab]*logp[lab] - 2.0*(true_sw & pred_near)
//                            + 1.5*(pred_sw & ~true_near & has_true_row & valid) )
// TOL=5 window, per-row edge-clipped.
//
// R16 post-mortem: MLP theory falsified (16 pinned loads, 120KB/CU in flight
// -> SLOWER). Six structures all read at ~2.2-2.4 TB/s; environmental floor
// (reads vs freshly-dirtied lines + writeback drain). So: minimize everything
// else. ONE kernel: per-row blocks, plain cached scalar loads (best-measured
// core), ballot masks in LDS, in-block window, last-block finisher via
// device-scope atomic counter (release/acquire threadfence). No extra
// launches, no mask HBM round-trip, no f64-CAS atomics (R2 lesson).

#define TOL 5
#define BLOCK 256
#define SROW 16384
#define NROWS 512

typedef unsigned long long u64;
typedef unsigned int u32;

// ---------------- single fused kernel ----------------
__global__ __launch_bounds__(BLOCK) void k_all(
    const float* __restrict__ logits, const int* __restrict__ labels,
    float* __restrict__ row_sum, int* __restrict__ row_cnt,
    u32* __restrict__ done, float* __restrict__ out)
{
    __shared__ u64 pm_s[BLOCK], tm_s[BLOCK], vm_s[BLOCK];   // 6 KB group masks
    __shared__ float wb[4];
    __shared__ int wv[4], rs[4], ps[4], hs[4];
    __shared__ int islast;

    const int tid = threadIdx.x;
    const int wave = tid >> 6;
    const int row = blockIdx.x;
    const long long rowbase = (long long)row * SROW;
    const float* lg = logits + 3 * rowbase;
    const int*   lb = labels + rowbase;

    float bsum = 0.f;
    int   vcnt = 0;

    // ---- phase A: stream row, CE + ballot masks (lane-contiguous loads) ----
#pragma unroll 4
    for (int i = 0; i < SROW / BLOCK; ++i) {      // 64 iterations
        const int pos = i * BLOCK + tid;
        const float l0 = lg[3 * pos + 0];
        const float l1 = lg[3 * pos + 1];
        const float l2 = lg[3 * pos + 2];
        const int lab = lb[pos];

        const bool valid = (lab != -100);
        const int ls = valid ? lab : 0;

        const float mx = fmaxf(l0, fmaxf(l1, l2));
        const float se = __expf(l0 - mx) + __expf(l1 - mx) + __expf(l2 - mx);
        const float lse = mx + __logf(se);
        const float lpick = (ls == 0 ? l0 : (ls == 1 ? l1 : l2)) - lse;
        const float w = (ls == 0) ? 0.1f : 5.0f;
        bsum += valid ? (-w * lpick) : 0.f;
        vcnt += valid ? 1 : 0;

        // argmax first-occurrence: pred>=1 iff max(l1,l2) > l0
        const bool psw = fmaxf(l1, l2) > l0;
        const bool tsw = (lab >= 1);              // -100 excluded

        const u64 pmm = __ballot(psw);
        const u64 tmm = __ballot(tsw);
        const u64 vmm = __ballot(valid);
        if ((tid & 63) == 0) {
            const int g = i * 4 + wave;           // group g = positions [64g, 64g+63]
            pm_s[g] = pmm; tm_s[g] = tmm; vm_s[g] = vmm;
        }
    }
    __syncthreads();

    // ---- phase B: windowed counts, thread t owns group t ----
    const u64 pm = pm_s[tid], tm = tm_s[tid], vm = vm_s[tid];
    const u64 pp = (tid > 0)         ? pm_s[tid - 1] : 0ULL;
    const u64 pn = (tid < BLOCK - 1) ? pm_s[tid + 1] : 0ULL;
    const u64 tp = (tid > 0)         ? tm_s[tid - 1] : 0ULL;
    const u64 tn = (tid < BLOCK - 1) ? tm_s[tid + 1] : 0ULL;

    u64 pnear = pm, tnear = tm;
#pragma unroll
    for (int k = 1; k <= TOL; ++k) {
        pnear |= (pm << k) | (pm >> k) | (pp >> (64 - k)) | (pn << (64 - k));
        tnear |= (tm << k) | (tm >> k) | (tp >> (64 - k)) | (tn << (64 - k));
    }

    int reward  = __popcll(tm & pnear);        // true_sw implies valid
    int penalty = __popcll(pm & ~tnear & vm);  // gated by valid
    int ht = (tm != 0ULL) ? 1 : 0;

#pragma unroll
    for (int off = 32; off; off >>= 1) {
        bsum    += __shfl_down(bsum, off);
        vcnt    += __shfl_down(vcnt, off);
        reward  += __shfl_down(reward, off);
        penalty += __shfl_down(penalty, off);
        ht      |= __shfl_down(ht, off);
    }
    if ((tid & 63) == 0) { wb[wave] = bsum; wv[wave] = vcnt; rs[wave] = reward; ps[wave] = penalty; hs[wave] = ht; }
    __syncthreads();

    // ---- publish row result + last-block election ----
    if (tid == 0) {
        float S = 0.f; int C = 0, R = 0, P = 0, H = 0;
#pragma unroll
        for (int i = 0; i < 4; ++i) { S += wb[i]; C += wv[i]; R += rs[i]; P += ps[i]; H |= hs[i]; }
        row_sum[row] = S - 2.0f * (float)R + (H ? 1.5f * (float)P : 0.0f);
        row_cnt[row] = C;
        __threadfence();                               // release: row data visible device-wide
        const u32 prev = atomicAdd(done, 1u);          // device-scope (m20)
        islast = (prev == (u32)(NROWS - 1)) ? 1 : 0;
    }
    __syncthreads();

    // ---- finisher: last block reduces 512 rows ----
    if (islast) {
        __threadfence();                               // acquire: see all rows
        double s = 0.0; long long c = 0;
        for (int i = tid; i < NROWS; i += BLOCK) {
            s += (double)row_sum[i];
            c += (long long)row_cnt[i];
        }
#pragma unroll
        for (int off = 32; off; off >>= 1) {
            s += __shfl_down(s, off);
            c += __shfl_down(c, off);
        }
        __shared__ double ss[4];
        __shared__ long long cs[4];
        if ((tid & 63) == 0) { ss[wave] = s; cs[wave] = c; }
        __syncthreads();
        if (tid == 0) {
            double S = 0.0; long long C = 0;
#pragma unroll
            for (int i = 0; i < 4; ++i) { S += ss[i]; C += cs[i]; }
            out[0] = (float)(S / (double)C);
        }
    }
}

extern "C" void kernel_launch(void* const* d_in, const int* in_sizes, int n_in,
                              void* d_out, int out_size, void* d_ws, size_t ws_size,
                              hipStream_t stream) {
    const float* logits = (const float*)d_in[0];
    const int*   labels = (const int*)d_in[1];
    float* out = (float*)d_out;

    char* ws = (char*)d_ws;
    float* row_sum = (float*)ws;                     // 2 KB
    int*   row_cnt = (int*)(row_sum + NROWS);        // 2 KB
    u32*   done    = (u32*)(row_cnt + NROWS);        // 4 B (poisoned 0xAA each call -> zero it)

    hipMemsetAsync(done, 0, sizeof(u32), stream);
    k_all<<<NROWS, BLOCK, 0, stream>>>(logits, labels, row_sum, row_cnt, done, out);
}